// Round 4
// baseline (493.200 us; speedup 1.0000x reference)
//
#include <hip/hip_runtime.h>
#include <stdint.h>

// Problem dims (fixed by reference)
#define TOKENS 8192
#define DIN    4096
#define DOUT   4096

typedef short bf16x8 __attribute__((ext_vector_type(8)));  // 8 bf16 = 4 VGPRs
typedef float f32x4  __attribute__((ext_vector_type(4)));  // MFMA 16x16 accum

// ---- fp32 -> bf16 round-to-nearest-even (inputs finite) ----
__device__ __forceinline__ unsigned short f2bf(float f) {
    union { float f; unsigned int u; } v; v.f = f;
    return (unsigned short)((v.u + 0x7fffu + ((v.u >> 16) & 1u)) >> 16);
}

// ---- ternary int {-1,0,1} -> bf16 bit pattern (2 selects, no float math) ----
__device__ __forceinline__ unsigned short tern2bf(int v) {
    return v == 0 ? (unsigned short)0u
                  : (v > 0 ? (unsigned short)0x3F80u : (unsigned short)0xBF80u);
}

// ---- async global->LDS, 16B/lane; LDS dest = wave-uniform base + lane*16 ----
__device__ __forceinline__ void gload_lds16(const unsigned short* g, unsigned short* l) {
    __builtin_amdgcn_global_load_lds(
        (const __attribute__((address_space(1))) unsigned int*)g,
        (__attribute__((address_space(3))) unsigned int*)l,
        16, 0, 0);
}

// ================= fused prologue: one kernel, two jobs =================
#define WBLKS 1024
#define XBLKS 2048

__global__ __launch_bounds__(256) void fused_cvt(
    const float* __restrict__ x, const int* __restrict__ W,
    unsigned short* __restrict__ xb, unsigned short* __restrict__ Wt) {
    __shared__ unsigned short lds[64][264];   // [n_local][k_local], pitch 264
    const int t = threadIdx.x;

    if (blockIdx.x < WBLKS) {
        // ---- W transpose part: tile k0..k0+255, n0..n0+63 ----
        const int b  = blockIdx.x;
        const int k0 = (b >> 6) * 256;        // 16 k-tiles
        const int n0 = (b & 63) * 64;         // 64 n-tiles
        const int nl = 4 * (t & 15);          // n_local base this thread fills
#pragma unroll
        for (int it = 0; it < 16; ++it) {
            const int r = (t >> 4) + 16 * it; // k_local
            int4 v = *(const int4*)&W[(size_t)(k0 + r) * DOUT + n0 + nl];
            lds[nl + 0][r] = tern2bf(v.x);
            lds[nl + 1][r] = tern2bf(v.y);
            lds[nl + 2][r] = tern2bf(v.z);
            lds[nl + 3][r] = tern2bf(v.w);
        }
        __syncthreads();
        const int n = t >> 2;                 // 0..63
        const int s = t & 3;
        unsigned short* drow = Wt + (size_t)(n0 + n) * DIN + k0;
#pragma unroll
        for (int u = 0; u < 8; ++u) {
            const int k = u * 32 + s * 8;     // lanes 0-3 cover 64B contiguous
            *(uint4*)&drow[k] = *(const uint4*)&lds[n][k];
        }
    } else {
        // ---- x convert part: 8 chunks of 8 floats per thread ----
        const int b2 = blockIdx.x - WBLKS;    // 0..2047
        const int stride = XBLKS * 256;       // chunks per sweep
        int c = b2 * 256 + t;
        const float4* x4 = (const float4*)x;
        uint4* o = (uint4*)xb;                // 8 bf16 = 16B per chunk
#pragma unroll
        for (int j = 0; j < 8; ++j, c += stride) {
            float4 a = x4[2 * c];
            float4 bvec = x4[2 * c + 1];
            uint4 p;
            p.x = (unsigned)f2bf(a.x)    | ((unsigned)f2bf(a.y) << 16);
            p.y = (unsigned)f2bf(a.z)    | ((unsigned)f2bf(a.w) << 16);
            p.z = (unsigned)f2bf(bvec.x) | ((unsigned)f2bf(bvec.y) << 16);
            p.w = (unsigned)f2bf(bvec.z) | ((unsigned)f2bf(bvec.w) << 16);
            o[c] = p;
        }
    }
}

// ================= main GEMM: 256x256, BK=64, faithful m201 8-phase =================
// C[M][N] = A[M][K] * Bt[N][K]^T. 512 threads = 8 waves (2M x 4N), wave tile
// 128x64 (8 Mf x 4 Nf of 16x16), acc = 128 regs. LDS 128 KiB double-buffered.
//
// Phase (m201-verified): [reads for THIS phase (4 or 12 ds_read_b128)]
//   [stage 1 half-tile (2 gload_lds/thread)] [vmcnt(4) at group-end phases only]
//   [lgkmcnt(8) on 12-read phases] BAR; lgkmcnt(0); setprio(1); 16 MFMA;
//   setprio(0); BAR.
// Reads of any buffer follow a barrier that follows ALL waves' confirming vmcnt
// (race-free by construction, unlike R3's read-ahead variant).
//
// Staging ledger (KEY: B's LDS is free right after its QD0 burst-read, so B is
// staged TWO K-tiles ahead; A one ahead). Per 8-phase iter (tiles t=2g, 2g+1):
//   p0: A(t+1)h0   p1: A(t+1)h1   p2: B(t+2)h0   p3: B(t+2)h1 + VM4
//   p4: A(t+2)h0   p5: A(t+2)h1   p6: B(t+3)h0   p7: B(t+3)h1 + VM4
// FIFO at p3: [A+1(4), B+2(4)] after older drained -> VM4 confirms A(t+1) (and
// B(t+1), older) needed at p4; leaves B(t+2) flying. FIFO at p7:
// [B+2(4), A+2(4), B+3(4)] -> VM4 confirms B+2, A+2 (needed next p0); leaves B+3.
// Never drains to 0 in the loop. WAR: stage of X follows BAR2 of the phase after
// X-old's last read phase (A-old read p4..p7 prev, staged p0; B-old read p0,
// staged p2) -- and lgkmcnt(0) before each MFMA guarantees reads EXECUTED before
// the overwriting gload (issued >= 2 barriers later) can land.
// Prologue: stage A0,B0,B1 (6 half-tiles), VM4 (confirm A0,B0; B1 flies), BAR.
// Tail: tiles 62,63 peeled; stage A63 at p0/p1, VM0 at p3.
#define BM 256
#define BN 256
#define BK 64

#define STAGE_A(bufi, h, kt)                                                        \
    do {                                                                            \
        gload_lds16(gA + (size_t)((h) * 128) * DIN + (kt),                          \
                    &sA[bufi][(h) * 8192 + wave * 1024]);                           \
        gload_lds16(gA + (size_t)((h) * 128 + 8) * DIN + (kt),                      \
                    &sA[bufi][(h) * 8192 + wave * 1024 + 512]);                     \
    } while (0)

#define STAGE_B(bufi, h, kt)                                                        \
    do {                                                                            \
        gload_lds16(gB + (size_t)((h) * 128) * DIN + (kt),                          \
                    &sB[bufi][(h) * 8192 + wave * 1024]);                           \
        gload_lds16(gB + (size_t)((h) * 128 + 8) * DIN + (kt),                      \
                    &sB[bufi][(h) * 8192 + wave * 1024 + 512]);                     \
    } while (0)

#define BAR __builtin_amdgcn_s_barrier()
#define VM4 asm volatile("s_waitcnt vmcnt(4)" ::: "memory")
#define VM0 asm volatile("s_waitcnt vmcnt(0)" ::: "memory")
#define LG8 asm volatile("s_waitcnt lgkmcnt(8)" ::: "memory")

// One phase: same-phase fragment consumption (m201-faithful).
#define PH(BUF, QD, STG, TAIL)                                                      \
    {                                                                               \
        if ((QD) == 0) {                                                            \
            _Pragma("unroll") for (int ni = 0; ni < 4; ++ni) {                      \
                bfr[ni][0] = *(const bf16x8*)&sB[BUF][rowB + ni * 1024 + q80];      \
                bfr[ni][1] = *(const bf16x8*)&sB[BUF][rowB + ni * 1024 + q81];      \
            }                                                                       \
        }                                                                           \
        bf16x8 af[2][2];                                                            \
        _Pragma("unroll") for (int m2 = 0; m2 < 2; ++m2) {                          \
            af[m2][0] = *(const bf16x8*)&sA[BUF][rowA + ((QD)*2 + m2) * 1024 + q80];\
            af[m2][1] = *(const bf16x8*)&sA[BUF][rowA + ((QD)*2 + m2) * 1024 + q81];\
        }                                                                           \
        STG;                                                                        \
        TAIL;                                                                       \
        if ((QD) == 0) LG8;                                                         \
        BAR;                                                                        \
        asm volatile("s_waitcnt lgkmcnt(0)" ::: "memory");                          \
        __builtin_amdgcn_s_setprio(1);                                              \
        _Pragma("unroll") for (int ks = 0; ks < 2; ++ks)                            \
            _Pragma("unroll") for (int m2 = 0; m2 < 2; ++m2)                        \
                _Pragma("unroll") for (int ni = 0; ni < 4; ++ni)                    \
                    acc[(QD)*2 + m2][ni] = __builtin_amdgcn_mfma_f32_16x16x32_bf16( \
                        af[m2][ks], bfr[ni][ks], acc[(QD)*2 + m2][ni], 0, 0, 0);    \
        __builtin_amdgcn_s_setprio(0);                                              \
        BAR;                                                                        \
    }

__global__ __launch_bounds__(512, 2) void gemm_bt(
    const unsigned short* __restrict__ A,   // [M][K] bf16
    const unsigned short* __restrict__ B,   // [N][K] bf16 (W transposed)
    float* __restrict__ C) {                // [M][N] fp32
    const int K = DIN, N = DOUT;

    __shared__ __align__(16) unsigned short sA[2][BM * BK];  // 2 x 32 KB
    __shared__ __align__(16) unsigned short sB[2][BN * BK];  // 2 x 32 KB

    const int tid  = threadIdx.x;
    const int wave = tid >> 6;
    const int lane = tid & 63;
    const int wm = wave >> 2;               // 0..1  (M)
    const int wn = wave & 3;                // 0..3  (N)

    // ---- T1: XCD-aware bijective block swizzle (512 wgs, 8 XCDs, 64/XCD) ----
    const int wg  = blockIdx.x + gridDim.x * blockIdx.y;   // hardware linear id
    const int xcd = wg & 7;
    const int idx = wg >> 3;                               // 0..63 within XCD
    const int bx  = (xcd & 1) * 8 + (idx & 7);             // 0..15  (N tiles)
    const int by  = (xcd >> 1) * 8 + (idx >> 3);           // 0..31  (M tiles)

    // ---- staging addressing: wave w stages rows 16w..16w+15 of each half ----
    const int lrow = lane >> 3;             // 0..7 row within 8-row chunk
    const int qsrc = (lane & 7) ^ lrow;     // pre-swizzled global k-quad
    const unsigned short* gA =
        A + (size_t)(by * BM + wave * 16 + lrow) * K + qsrc * 8;
    const unsigned short* gB =
        B + (size_t)(bx * BN + wave * 16 + lrow) * K + qsrc * 8;

    // ---- fragment read addressing (swizzled ds_read) ----
    const int mrow = lane & 15;
    const int kgrp = lane >> 4;             // 0..3
    const int xr   = lane & 7;              // = row&7 of the frag row
    const int q80  = ((kgrp ^ xr) << 3);        // ks=0 swizzled quad * 8
    const int q81  = (((4 | kgrp) ^ xr) << 3);  // ks=1
    const int rowA = (wm * 128 + mrow) << 6;    // *64 elems/row
    const int rowB = (wn * 64 + mrow) << 6;

    f32x4 acc[8][4];
#pragma unroll
    for (int i = 0; i < 8; ++i)
#pragma unroll
        for (int j = 0; j < 4; ++j) {
            f32x4 z = {0.f, 0.f, 0.f, 0.f};
            acc[i][j] = z;
        }
    bf16x8 bfr[4][2];     // B-frags: resident across a K-tile's 4 phases

    // ---- prologue: A0, B0 (tile0) + B1 (tile1 B, two-ahead pattern) ----
    STAGE_A(0, 0, 0);
    STAGE_A(0, 1, 0);
    STAGE_B(0, 0, 0);
    STAGE_B(0, 1, 0);
    STAGE_B(1, 0, 64);
    STAGE_B(1, 1, 64);
    VM4;                  // confirm A0,B0; B1 (4 loads) stays in flight
    BAR;

    // ---- main loop: g = 0..30 (tiles 0..61), branch-free ----
    for (int kt = 0; kt + 256 <= K; kt += 128) {
        PH(0, 0, STAGE_A(1, 0, kt + 64), )       // p0
        PH(0, 1, STAGE_A(1, 1, kt + 64), )       // p1
        PH(0, 2, STAGE_B(0, 0, kt + 128), )      // p2
        PH(0, 3, STAGE_B(0, 1, kt + 128), VM4)   // p3
        PH(1, 0, STAGE_A(0, 0, kt + 128), )      // p4
        PH(1, 1, STAGE_A(0, 1, kt + 128), )      // p5
        PH(1, 2, STAGE_B(1, 0, kt + 192), )      // p6
        PH(1, 3, STAGE_B(1, 1, kt + 192), VM4)   // p7
    }

    // ---- peeled tail: tiles 62 (buf0) and 63 (buf1) ----
    PH(0, 0, STAGE_A(1, 0, K - 64), )
    PH(0, 1, STAGE_A(1, 1, K - 64), )
    PH(0, 2, , )
    PH(0, 3, , VM0)       // drain: A63 (+ already-confirmed B63) complete
    PH(1, 0, , )
    PH(1, 1, , )
    PH(1, 2, , )
    PH(1, 3, , )

    // ---- epilogue: C/D layout col=lane&15, row=(lane>>4)*4+reg; NT stores ----
    float* Cw = C + (size_t)(by * BM + wm * 128 + kgrp * 4) * N
                + (size_t)(bx * BN + wn * 64 + mrow);
#pragma unroll
    for (int mi = 0; mi < 8; ++mi)
#pragma unroll
        for (int ni = 0; ni < 4; ++ni)
#pragma unroll
            for (int r = 0; r < 4; ++r)
                __builtin_nontemporal_store(acc[mi][ni][r],
                                            &Cw[(size_t)(mi * 16 + r) * N + ni * 16]);
}

// ============ safety-net fallback if ws is too small (slow but correct) ============
__global__ void gemm_naive(const float* __restrict__ x, const int* __restrict__ W,
                           float* __restrict__ out) {
    int n = blockIdx.x * blockDim.x + threadIdx.x;
    int t = blockIdx.y;
    const float* xr = x + (size_t)t * DIN;
    float acc = 0.f;
    for (int k = 0; k < DIN; ++k)
        acc += xr[k] * (float)W[(size_t)k * DOUT + n];
    out[(size_t)t * DOUT + n] = acc;
}

extern "C" void kernel_launch(void* const* d_in, const int* in_sizes, int n_in,
                              void* d_out, int out_size, void* d_ws, size_t ws_size,
                              hipStream_t stream) {
    const float* x = (const float*)d_in[0];
    const int*   W = (const int*)d_in[1];
    float* out = (float*)d_out;

    const size_t xb_elems = (size_t)TOKENS * DIN;           // 64 MB bf16
    const size_t wt_elems = (size_t)DIN * DOUT;             // 32 MB bf16
    const size_t need = (xb_elems + wt_elems) * sizeof(unsigned short);

    if (ws_size < need) {   // should not happen; correctness safety net
        dim3 g(DOUT / 256, TOKENS);
        gemm_naive<<<g, 256, 0, stream>>>(x, W, out);
        return;
    }

    unsigned short* xb = (unsigned short*)d_ws;
    unsigned short* Wt = xb + xb_elems;

    fused_cvt<<<WBLKS + XBLKS, 256, 0, stream>>>(x, W, xb, Wt);

    dim3 grid(DOUT / BN, TOKENS / BM);   // (16, 32)
    gemm_bt<<<grid, 512, 0, stream>>>(xb, Wt, out);
}